// Round 8
// baseline (167.561 us; speedup 1.0000x reference)
//
#include <hip/hip_runtime.h>
#include <hip/hip_bf16.h>
#include <stdint.h>

typedef __bf16 bf16;
typedef __bf16 bf16x8 __attribute__((ext_vector_type(8)));
typedef __bf16 bf16x4 __attribute__((ext_vector_type(4)));
typedef float floatx4 __attribute__((ext_vector_type(4)));
typedef short short4v __attribute__((ext_vector_type(4)));

#define T_DIM 2048
#define C_DIM 1024
#define NH    16
#define HD    64

__device__ __forceinline__ void gload_lds16(const void* g, void* l) {
    __builtin_amdgcn_global_load_lds(
        (__attribute__((address_space(1))) void*)(g),
        (__attribute__((address_space(3))) void*)(l),
        16, 0, 0);
}

#define MFMA16(a, b, c)  __builtin_amdgcn_mfma_f32_16x16x32_bf16(a, b, c, 0, 0, 0)
#define MFMAK16(a, b, c) __builtin_amdgcn_mfma_f32_16x16x16bf16_1k(a, b, c, 0, 0, 0)

// ---------------------------------------------------------------------------
// Fused f32 -> bf16 convert for x (2M), w_attn (3M), w_proj (1M); 8 elem/thread
// ---------------------------------------------------------------------------
__global__ __launch_bounds__(256) void cvt_all(
    const float* __restrict__ x, const float* __restrict__ wa,
    const float* __restrict__ wp,
    bf16* __restrict__ xb, bf16* __restrict__ wab, bf16* __restrict__ wpb)
{
    const int i = blockIdx.x * 256 + threadIdx.x;     // < 786432
    const float* src; bf16* dst; int off;
    if (i < 262144)      { src = x;  dst = xb;  off = i; }
    else if (i < 655360) { src = wa; dst = wab; off = i - 262144; }
    else                 { src = wp; dst = wpb; off = i - 655360; }
    const float4 a = ((const float4*)src)[off * 2];
    const float4 b = ((const float4*)src)[off * 2 + 1];
    bf16x8 o;
    o[0] = (bf16)a.x; o[1] = (bf16)a.y; o[2] = (bf16)a.z; o[3] = (bf16)a.w;
    o[4] = (bf16)b.x; o[5] = (bf16)b.y; o[6] = (bf16)b.z; o[7] = (bf16)b.w;
    *(bf16x8*)(dst + (size_t)off * 8) = o;
}

// ---------------------------------------------------------------------------
// NT GEMM: out[m,n] = sum_k A[m,k]*B[n,k] + bias[n].  A: Mx1024, B: Nx1024 bf16.
// Tiles 128 x TN. TN=64: 4 waves of 32x64 (MT=2,NT=4).
// MODE 0: N=3072. Scatter Q->[h][t][d], K->[h][t][d], V->Vt[h][d][t].
// MODE 1: N=1024, f32 row-major store (proj output).
// ---------------------------------------------------------------------------
template<int MODE, int TN>
__global__ __launch_bounds__(256) void csa_gemm_bt(
    const bf16* __restrict__ A, const bf16* __restrict__ B,
    const float* __restrict__ bias,
    void* __restrict__ out0v, bf16* __restrict__ out1, bf16* __restrict__ out2)
{
    constexpr int K = 1024;
    constexpr int MT = (TN == 128) ? 4 : 2;
    __shared__ __align__(16) bf16 sA[128 * 32];
    __shared__ __align__(16) bf16 sB[TN * 32];

    const int tid  = threadIdx.x;
    const int lane = tid & 63;
    const int wid  = tid >> 6;
    const int rowbase = (TN == 128) ? (wid & 1) * 64 : wid * 32;
    const int colbase = (TN == 128) ? (wid >> 1) * 64 : 0;
    const int tileM = blockIdx.x * 128;
    const int tileN = blockIdx.y * TN;

    const int r0 = tid >> 2;
    const int c0 = (tid & 3) * 8;
    const long aBase = (long)(tileM + r0) * K + c0;
    const long bBase = (long)(tileN + r0) * K + c0;

    const int fr   = lane & 15;
    const int quad = lane >> 4;
    const int fc   = quad * 8;

    floatx4 acc[MT][4];
#pragma unroll
    for (int i = 0; i < MT; i++)
#pragma unroll
        for (int j = 0; j < 4; j++) acc[i][j] = (floatx4){0.f, 0.f, 0.f, 0.f};

    for (int k0 = 0; k0 < K; k0 += 32) {
        __syncthreads();
        gload_lds16(A + aBase + k0,                 sA + tid * 8);
        gload_lds16(A + aBase + (long)64 * K + k0,  sA + 2048 + tid * 8);
        gload_lds16(B + bBase + k0,                 sB + tid * 8);
        if (TN == 128)
            gload_lds16(B + bBase + (long)64 * K + k0, sB + 2048 + tid * 8);
        __syncthreads();

        bf16x8 af[MT], bfr[4];
#pragma unroll
        for (int mt = 0; mt < MT; mt++)
            af[mt] = *(const bf16x8*)(sA + (rowbase + mt * 16 + fr) * 32 + fc);
#pragma unroll
        for (int nt = 0; nt < 4; nt++)
            bfr[nt] = *(const bf16x8*)(sB + (colbase + nt * 16 + fr) * 32 + fc);
#pragma unroll
        for (int mt = 0; mt < MT; mt++)
#pragma unroll
            for (int nt = 0; nt < 4; nt++)
                acc[mt][nt] = MFMA16(af[mt], bfr[nt], acc[mt][nt]);
    }

    // epilogue: C/D layout col = lane&15, row = quad*4 + reg
#pragma unroll
    for (int mt = 0; mt < MT; mt++) {
#pragma unroll
        for (int nt = 0; nt < 4; nt++) {
            const int gn = tileN + colbase + nt * 16 + fr;
            const float bv = bias[gn];
            const int gmb = tileM + rowbase + mt * 16 + quad * 4;
            if (MODE == 0) {
                const int which = gn >> 10;
                const int w2 = gn & 1023;
                const int hh = w2 >> 6, d = w2 & 63;
                if (which == 2) {
                    bf16x4 pk;
#pragma unroll
                    for (int r = 0; r < 4; r++) pk[r] = (bf16)(acc[mt][nt][r] + bv);
                    *(bf16x4*)(out2 + ((long)(hh * HD + d) << 11) + gmb) = pk;
                } else {
                    bf16* dst = (which == 0) ? (bf16*)out0v : out1;
#pragma unroll
                    for (int r = 0; r < 4; r++)
                        dst[((long)hh * T_DIM + gmb + r) * HD + d] =
                            (bf16)(acc[mt][nt][r] + bv);
                }
            } else {
#pragma unroll
                for (int r = 0; r < 4; r++)
                    ((float*)out0v)[(long)(gmb + r) * C_DIM + gn] =
                        acc[mt][nt][r] + bv;
            }
        }
    }
}

// ---------------------------------------------------------------------------
// Chunked causal flash attention, k-sliced waves (no-max softmax).
// grid (c=4, h=16, z=32); qt = 31 - z (heavy first). Chunk c covers k-tiles
// [8c, min(8c+8, qt+1)).
// Each wave owns k-slice [wid*16, wid*16+16) of every 64-k tile:
//   QK: reads only its 2 b128 K rows; S^T C-layout (q=lane&15, k=quad*4+r)
//   IS the A-layout of the K=16 MFMA -> P stays in registers (no round-trip).
//   PV: b64 V^T reads of its own slice; accumulates full 64x64 O per wave.
// Block end: butterfly reduce O across the 4 waves via LDS (aliases staging
// buffers), reduce l via small LDS array; wave w finalizes q-group w.
// ---------------------------------------------------------------------------
__global__ __launch_bounds__(256) void csa_attn_chunk(
    const bf16* __restrict__ Qh, const bf16* __restrict__ Kh,
    const bf16* __restrict__ Vth, float* __restrict__ Opart,
    float* __restrict__ lpart, bf16* __restrict__ YY)
{
    // staging (32 KB) aliased by reduce regions (8 x 64x20 f32 = 40 KB) + sL
    __shared__ __align__(16) char smem[41984];
    bf16* sK0 = (bf16*)(smem);
    bf16* sK1 = (bf16*)(smem + 8192);
    bf16* sV0 = (bf16*)(smem + 16384);
    bf16* sV1 = (bf16*)(smem + 24576);
    float* sR = (float*)smem;                 // 8 regions x 1280 f32 (stride 20)
    float* sL = (float*)(smem + 40960);       // [4][64]

    const int c  = blockIdx.x;
    const int h  = blockIdx.y;
    const int qt = 31 - (int)blockIdx.z;      // heavy q-tiles first
    const int nk = qt + 1;
    const int kt0 = c * 8;
    if (kt0 >= nk) return;
    const int ktend = (kt0 + 8 < nk) ? kt0 + 8 : nk;

    const int tid  = threadIdx.x;
    const int lane = tid & 63;
    const int wid  = tid >> 6;
    const int fr   = lane & 15;
    const int quad = lane >> 4;
    const int f7   = fr & 7;
    const int q0   = qt * 64;

    // Q B-fragments for ALL 4 q-groups (wave needs all q's for its k-slice)
    bf16x8 qf[4][2];
#pragma unroll
    for (int g = 0; g < 4; g++) {
        const bf16* qrow = Qh + ((long)h * T_DIM + q0 + g * 16 + fr) * HD;
        qf[g][0] = *(const bf16x8*)(qrow + quad * 8);
        qf[g][1] = *(const bf16x8*)(qrow + quad * 8 + 32);
    }

    // staging: thread covers 16B chunk (row rb+32i, chunk tid&7), XOR-swizzled
    const int rb   = tid >> 3;                 // 0..31
    const int cswz = (tid & 7) ^ (rb & 7);

    auto stage = [&](bf16* sKd, bf16* sVd, int k0) {
        gload_lds16(Kh + ((long)(h * T_DIM + k0 + rb) << 6) + cswz * 8,
                    sKd + tid * 8);
        gload_lds16(Kh + ((long)(h * T_DIM + k0 + rb + 32) << 6) + cswz * 8,
                    sKd + 2048 + tid * 8);
        gload_lds16(Vth + ((long)(h * HD + rb) << 11) + k0 + cswz * 8,
                    sVd + tid * 8);
        gload_lds16(Vth + ((long)(h * HD + rb + 32) << 11) + k0 + cswz * 8,
                    sVd + 2048 + tid * 8);
    };

    stage(sK0, sV0, kt0 * 64);

    float l_i[4] = {0.f, 0.f, 0.f, 0.f};
    floatx4 o_acc[4][4];                       // [q-group][d-group]
#pragma unroll
    for (int g = 0; g < 4; g++)
#pragma unroll
        for (int gd = 0; gd < 4; gd++) o_acc[g][gd] = (floatx4){0.f, 0.f, 0.f, 0.f};

    for (int kt = kt0; kt < ktend; ++kt) {
        const int it = kt - kt0;
        __syncthreads();
        if (kt + 1 < ktend)
            stage((it & 1) ? sK0 : sK1, (it & 1) ? sV0 : sV1, (kt + 1) * 64);
        const bf16* K_ = (it & 1) ? sK1 : sK0;
        const bf16* V_ = (it & 1) ? sV1 : sV0;
        const int k0 = kt * 64;
        const bool diag = (kt == qt);

        // QK for my k-slice: A = K rows [wid*16+fr], B = Q groups (regs)
        const bf16* kr = K_ + (wid * 16 + fr) * 64;
        const bf16x8 ka0 = *(const bf16x8*)(kr + (quad ^ f7) * 8);
        const bf16x8 ka1 = *(const bf16x8*)(kr + ((quad + 4) ^ f7) * 8);
        const int kg = k0 + wid * 16 + quad * 4;   // lane's k base (+r)

        short4v pa[4];
#pragma unroll
        for (int g = 0; g < 4; g++) {
            floatx4 z = (floatx4){0.f, 0.f, 0.f, 0.f};
            z = MFMA16(ka0, qf[g][0], z);
            z = MFMA16(ka1, qf[g][1], z);
            const int qg = q0 + g * 16 + fr;
            bf16x4 pk;
            float s = 0.f;
#pragma unroll
            for (int r = 0; r < 4; r++) {
                const float e = __builtin_amdgcn_exp2f(z[r] * 0.1803368801f);
                const float pv = (!diag || (kg + r <= qg)) ? e : 0.f;
                s += pv;
                pk[r] = (bf16)pv;
            }
            s += __shfl_xor(s, 16);
            s += __shfl_xor(s, 32);
            l_i[g] += s;                        // partial over my k-slice
            pa[g] = __builtin_bit_cast(short4v, pk);
        }

        // PV (K=16): B = V^T[d = gd*16 + lane&15][k = my slice + quad*4 + j]
        const int vchunk = ((wid * 2 + (quad >> 1)) ^ f7) * 8 + (quad & 1) * 4;
#pragma unroll
        for (int gd = 0; gd < 4; gd++) {
            const bf16* vrow = V_ + (gd * 16 + fr) * 64;
            const short4v vbs = __builtin_bit_cast(short4v,
                                    *(const bf16x4*)(vrow + vchunk));
#pragma unroll
            for (int g = 0; g < 4; g++)
                o_acc[g][gd] = MFMAK16(pa[g], vbs, o_acc[g][gd]);
        }
    }

    // ---- cross-wave reduction (staging buffers are dead -> reuse as sR) ----
    __syncthreads();
    // l partials
    if (quad == 0) {
#pragma unroll
        for (int g = 0; g < 4; g++) sL[wid * 64 + g * 16 + fr] = l_i[g];
    }
    // butterfly step 1: exchange with partner wid^2 (by q-side)
    const int side = wid >> 1;
#pragma unroll
    for (int g = 0; g < 4; g++) {
        if ((g >> 1) != side) {
            float* R = sR + (wid * 2 + (g & 1)) * 1280;
#pragma unroll
            for (int gd = 0; gd < 4; gd++)
                *(floatx4*)(R + (gd * 16 + fr) * 20 + quad * 4) = o_acc[g][gd];
        }
    }
    __syncthreads();
#pragma unroll
    for (int g = 0; g < 4; g++) {
        if ((g >> 1) == side) {
            const float* R = sR + ((wid ^ 2) * 2 + (g & 1)) * 1280;
#pragma unroll
            for (int gd = 0; gd < 4; gd++)
                o_acc[g][gd] += *(const floatx4*)(R + (gd * 16 + fr) * 20 + quad * 4);
        }
    }
    __syncthreads();
    // butterfly step 2: exchange with partner wid^1
#pragma unroll
    for (int g = 0; g < 4; g++) {
        if (g == (wid ^ 1)) {
            float* R = sR + wid * 1280;
#pragma unroll
            for (int gd = 0; gd < 4; gd++)
                *(floatx4*)(R + (gd * 16 + fr) * 20 + quad * 4) = o_acc[g][gd];
        }
    }
    __syncthreads();
#pragma unroll
    for (int g = 0; g < 4; g++) {
        if (g == wid) {
            const float* R = sR + (wid ^ 1) * 1280;
#pragma unroll
            for (int gd = 0; gd < 4; gd++)
                o_acc[g][gd] += *(const floatx4*)(R + (gd * 16 + fr) * 20 + quad * 4);
        }
    }

    // l: sum over the 4 waves for my final q-group (= wid)
    const float lf = sL[0 * 64 + wid * 16 + fr] + sL[1 * 64 + wid * 16 + fr] +
                     sL[2 * 64 + wid * 16 + fr] + sL[3 * 64 + wid * 16 + fr];

    if (kt0 == 0 && ktend == nk) {
        // single-chunk q-tile: normalize and write YY directly
        const float inv_self = 1.f / lf;
        float inv[4];
#pragma unroll
        for (int r = 0; r < 4; r++) inv[r] = __shfl(inv_self, quad * 4 + r);
#pragma unroll
        for (int g = 0; g < 4; g++) {
            if (g == wid) {
#pragma unroll
                for (int r = 0; r < 4; r++) {
                    const int q = q0 + g * 16 + quad * 4 + r;
                    const int rq = q >> 10, cq = q & 1023;
#pragma unroll
                    for (int gd = 0; gd < 4; gd++) {
                        const int d = gd * 16 + fr;
                        YY[(long)(h * 128 + 2 * d + rq) * 1024 + cq] =
                            (bf16)(o_acc[g][gd][r] * inv[r]);
                    }
                }
            }
        }
    } else {
        // partial store: O (f32, unnormalized) + l
        const long obase = ((long)((h * 32 + qt) * 4 + c)) * 4096;
#pragma unroll
        for (int g = 0; g < 4; g++) {
            if (g == wid) {
#pragma unroll
                for (int gd = 0; gd < 4; gd++)
#pragma unroll
                    for (int r = 0; r < 4; r++)
                        Opart[obase + (g * 16 + quad * 4 + r) * 64 + gd * 16 + fr] =
                            o_acc[g][gd][r];
            }
        }
        if (quad == 0)
            lpart[((h * 32 + qt) * 4 + c) * 64 + wid * 16 + fr] = lf;
    }
}

// ---------------------------------------------------------------------------
// Combine partials for qt >= 8: sum <=4 chunks, normalize, write YY.
// grid (24, 16): qt = blockIdx.x + 8.
// ---------------------------------------------------------------------------
__global__ __launch_bounds__(256) void csa_combine(
    const float* __restrict__ Opart, const float* __restrict__ lpart,
    bf16* __restrict__ YY)
{
    const int qt = blockIdx.x + 8;
    const int h  = blockIdx.y;
    const int nc = (qt >> 3) + 1;               // 2..4
    const int t  = threadIdx.x;
    const int q  = t >> 2;                      // 0..63
    const int d0 = (t & 3) * 16;

    const long obase = ((long)((h * 32 + qt) * 4)) * 4096 + q * 64 + d0;
    const int  lbase = (h * 32 + qt) * 4 * 64 + q;

    float4 acc[4] = {};
    float lq = 0.f;
    for (int c = 0; c < nc; c++) {
        const float4* src = (const float4*)(Opart + obase + (long)c * 4096);
#pragma unroll
        for (int j = 0; j < 4; j++) {
            const float4 v = src[j];
            acc[j].x += v.x; acc[j].y += v.y; acc[j].z += v.z; acc[j].w += v.w;
        }
        lq += lpart[lbase + c * 64];
    }
    const float inv = 1.f / lq;
    const int qglob = qt * 64 + q;
    const int rq = qglob >> 10, cq = qglob & 1023;
#pragma unroll
    for (int j = 0; j < 4; j++) {
        const float vv[4] = {acc[j].x, acc[j].y, acc[j].z, acc[j].w};
#pragma unroll
        for (int k = 0; k < 4; k++) {
            const int d = d0 + j * 4 + k;
            YY[(long)(h * 128 + 2 * d + rq) * 1024 + cq] = (bf16)(vv[k] * inv);
        }
    }
}

extern "C" void kernel_launch(void* const* d_in, const int* in_sizes, int n_in,
                              void* d_out, int out_size, void* d_ws, size_t ws_size,
                              hipStream_t stream) {
    (void)in_sizes; (void)n_in; (void)out_size; (void)ws_size;
    const float* x      = (const float*)d_in[0];
    const float* w_attn = (const float*)d_in[1];
    const float* b_attn = (const float*)d_in[2];
    const float* w_proj = (const float*)d_in[3];
    const float* b_proj = (const float*)d_in[4];

    // workspace layout
    bf16* xb  = (bf16*)d_ws;                          // [T][C]
    bf16* wab = xb  + (size_t)T_DIM * C_DIM;          // [3C][C]
    bf16* wpb = wab + (size_t)3 * C_DIM * C_DIM;      // [C][C]
    bf16* Q   = wpb + (size_t)C_DIM * C_DIM;          // [NH][T][HD]
    bf16* Kp  = Q   + (size_t)NH * T_DIM * HD;        // [NH][T][HD]
    bf16* Vt  = Kp  + (size_t)NH * T_DIM * HD;        // [NH][HD][T]
    bf16* YY  = Vt  + (size_t)NH * T_DIM * HD;        // [T][C] permuted pre-proj
    float* Opart = (float*)(YY + (size_t)T_DIM * C_DIM);   // [16][32][4][64][64]
    float* lpart = Opart + (size_t)16 * 32 * 4 * 4096;     // [16][32][4][64]

    // fused f32->bf16 conversion (x, w_attn, w_proj)
    cvt_all<<<3072, 256, 0, stream>>>(x, w_attn, w_proj, xb, wab, wpb);

    // qkv projection: 128x64 tiles -> 768 blocks = 3/CU balanced
    csa_gemm_bt<0, 64><<<dim3(16, 48), 256, 0, stream>>>(xb, wab, b_attn, Q, Kp, Vt);
    // chunked causal flash attention (k-sliced waves, heavy-first) + combine
    csa_attn_chunk<<<dim3(4, NH, 32), 256, 0, stream>>>(Q, Kp, Vt, Opart, lpart, YY);
    csa_combine<<<dim3(24, NH), 256, 0, stream>>>(Opart, lpart, YY);
    // output projection: yy @ w_proj^T + b_proj -> f32 out
    csa_gemm_bt<1, 64><<<dim3(16, 16), 256, 0, stream>>>(YY, wpb, b_proj, d_out, nullptr, nullptr);
}

// Round 9
// 155.297 us; speedup vs baseline: 1.0790x; 1.0790x over previous
//
#include <hip/hip_runtime.h>
#include <hip/hip_bf16.h>
#include <stdint.h>

typedef __bf16 bf16;
typedef __bf16 bf16x8 __attribute__((ext_vector_type(8)));
typedef __bf16 bf16x4 __attribute__((ext_vector_type(4)));
typedef float floatx4 __attribute__((ext_vector_type(4)));
typedef short short4v __attribute__((ext_vector_type(4)));

#define T_DIM 2048
#define C_DIM 1024
#define NH    16
#define HD    64

__device__ __forceinline__ void gload_lds16(const void* g, void* l) {
    __builtin_amdgcn_global_load_lds(
        (__attribute__((address_space(1))) void*)(g),
        (__attribute__((address_space(3))) void*)(l),
        16, 0, 0);
}

#define MFMA16(a, b, c)  __builtin_amdgcn_mfma_f32_16x16x32_bf16(a, b, c, 0, 0, 0)
#define MFMAK16(a, b, c) __builtin_amdgcn_mfma_f32_16x16x16bf16_1k(a, b, c, 0, 0, 0)

// ---------------------------------------------------------------------------
// Fused f32 -> bf16 convert for x (2M), w_attn (3M), w_proj (1M); 8 elem/thread
// ---------------------------------------------------------------------------
__global__ __launch_bounds__(256) void cvt_all(
    const float* __restrict__ x, const float* __restrict__ wa,
    const float* __restrict__ wp,
    bf16* __restrict__ xb, bf16* __restrict__ wab, bf16* __restrict__ wpb)
{
    const int i = blockIdx.x * 256 + threadIdx.x;     // < 786432
    const float* src; bf16* dst; int off;
    if (i < 262144)      { src = x;  dst = xb;  off = i; }
    else if (i < 655360) { src = wa; dst = wab; off = i - 262144; }
    else                 { src = wp; dst = wpb; off = i - 655360; }
    const float4 a = ((const float4*)src)[off * 2];
    const float4 b = ((const float4*)src)[off * 2 + 1];
    bf16x8 o;
    o[0] = (bf16)a.x; o[1] = (bf16)a.y; o[2] = (bf16)a.z; o[3] = (bf16)a.w;
    o[4] = (bf16)b.x; o[5] = (bf16)b.y; o[6] = (bf16)b.z; o[7] = (bf16)b.w;
    *(bf16x8*)(dst + (size_t)off * 8) = o;
}

// ---------------------------------------------------------------------------
// NT GEMM: out[m,n] = sum_k A[m,k]*B[n,k] + bias[n].  A: Mx1024, B: Nx1024 bf16.
// Tiles 128 x TN. TN=64: 4 waves of 32x64 (MT=2,NT=4).
// MODE 0: N=3072. Scatter Q->[h][t][d], K->[h][t][d], V->Vt[h][d][t].
// MODE 1: N=1024, f32 row-major store (proj output).
// ---------------------------------------------------------------------------
template<int MODE, int TN>
__global__ __launch_bounds__(256) void csa_gemm_bt(
    const bf16* __restrict__ A, const bf16* __restrict__ B,
    const float* __restrict__ bias,
    void* __restrict__ out0v, bf16* __restrict__ out1, bf16* __restrict__ out2)
{
    constexpr int K = 1024;
    constexpr int MT = (TN == 128) ? 4 : 2;
    __shared__ __align__(16) bf16 sA[128 * 32];
    __shared__ __align__(16) bf16 sB[TN * 32];

    const int tid  = threadIdx.x;
    const int lane = tid & 63;
    const int wid  = tid >> 6;
    const int rowbase = (TN == 128) ? (wid & 1) * 64 : wid * 32;
    const int colbase = (TN == 128) ? (wid >> 1) * 64 : 0;
    const int tileM = blockIdx.x * 128;
    const int tileN = blockIdx.y * TN;

    const int r0 = tid >> 2;
    const int c0 = (tid & 3) * 8;
    const long aBase = (long)(tileM + r0) * K + c0;
    const long bBase = (long)(tileN + r0) * K + c0;

    const int fr   = lane & 15;
    const int quad = lane >> 4;
    const int fc   = quad * 8;

    floatx4 acc[MT][4];
#pragma unroll
    for (int i = 0; i < MT; i++)
#pragma unroll
        for (int j = 0; j < 4; j++) acc[i][j] = (floatx4){0.f, 0.f, 0.f, 0.f};

    for (int k0 = 0; k0 < K; k0 += 32) {
        __syncthreads();
        gload_lds16(A + aBase + k0,                 sA + tid * 8);
        gload_lds16(A + aBase + (long)64 * K + k0,  sA + 2048 + tid * 8);
        gload_lds16(B + bBase + k0,                 sB + tid * 8);
        if (TN == 128)
            gload_lds16(B + bBase + (long)64 * K + k0, sB + 2048 + tid * 8);
        __syncthreads();

        bf16x8 af[MT], bfr[4];
#pragma unroll
        for (int mt = 0; mt < MT; mt++)
            af[mt] = *(const bf16x8*)(sA + (rowbase + mt * 16 + fr) * 32 + fc);
#pragma unroll
        for (int nt = 0; nt < 4; nt++)
            bfr[nt] = *(const bf16x8*)(sB + (colbase + nt * 16 + fr) * 32 + fc);
#pragma unroll
        for (int mt = 0; mt < MT; mt++)
#pragma unroll
            for (int nt = 0; nt < 4; nt++)
                acc[mt][nt] = MFMA16(af[mt], bfr[nt], acc[mt][nt]);
    }

    // epilogue: C/D layout col = lane&15, row = quad*4 + reg
#pragma unroll
    for (int mt = 0; mt < MT; mt++) {
#pragma unroll
        for (int nt = 0; nt < 4; nt++) {
            const int gn = tileN + colbase + nt * 16 + fr;
            const float bv = bias[gn];
            const int gmb = tileM + rowbase + mt * 16 + quad * 4;
            if (MODE == 0) {
                const int which = gn >> 10;
                const int w2 = gn & 1023;
                const int hh = w2 >> 6, d = w2 & 63;
                if (which == 2) {
                    bf16x4 pk;
#pragma unroll
                    for (int r = 0; r < 4; r++) pk[r] = (bf16)(acc[mt][nt][r] + bv);
                    *(bf16x4*)(out2 + ((long)(hh * HD + d) << 11) + gmb) = pk;
                } else {
                    bf16* dst = (which == 0) ? (bf16*)out0v : out1;
#pragma unroll
                    for (int r = 0; r < 4; r++)
                        dst[((long)hh * T_DIM + gmb + r) * HD + d] =
                            (bf16)(acc[mt][nt][r] + bv);
                }
            } else {
#pragma unroll
                for (int r = 0; r < 4; r++)
                    ((float*)out0v)[(long)(gmb + r) * C_DIM + gn] =
                        acc[mt][nt][r] + bv;
            }
        }
    }
}

// ---------------------------------------------------------------------------
// Chunked causal flash attention (no-max softmax -> partials ADDITIVE).
// grid (c=4, h=16, z=32); qt = 31 - z so heaviest chunks dispatch FIRST.
// Chunk c covers k-tiles [8c, min(8c+8, qt+1)). Wave owns 16 q-rows, all k.
// P stays in REGISTERS: S^T C-layout (q=lane&15, k=quad*4+r) is exactly the
// K=16 MFMA A-operand layout, so PV uses mfma_16x16x16bf16_1k with A=p[nt]
// and B = b64 V^T reads -- no P LDS round-trip, no lgkmcnt(0) bubble.
// LDS 32 KB -> 5 blocks/CU resident.
// ---------------------------------------------------------------------------
__global__ __launch_bounds__(256) void csa_attn_chunk(
    const bf16* __restrict__ Qh, const bf16* __restrict__ Kh,
    const bf16* __restrict__ Vth, float* __restrict__ Opart,
    float* __restrict__ lpart, bf16* __restrict__ YY)
{
    __shared__ __align__(16) bf16 sK[2][64 * 64];
    __shared__ __align__(16) bf16 sV[2][64 * 64];

    const int c  = blockIdx.x;
    const int h  = blockIdx.y;
    const int qt = 31 - (int)blockIdx.z;         // heavy q-tiles first
    const int nk = qt + 1;
    const int kt0 = c * 8;
    if (kt0 >= nk) return;                       // invalid chunk
    const int ktend = (kt0 + 8 < nk) ? kt0 + 8 : nk;

    const int tid  = threadIdx.x;
    const int lane = tid & 63;
    const int wid  = tid >> 6;
    const int fr   = lane & 15;
    const int quad = lane >> 4;
    const int f7   = fr & 7;
    const int q0   = qt * 64;
    const int qg   = q0 + wid * 16 + fr;

    // Q B-fragments: B[n=lane&15=q][k=quad*8+j] = Q[qg][d]
    const bf16* qrow = Qh + ((long)h * T_DIM + qg) * HD;
    const bf16x8 qf0 = *(const bf16x8*)(qrow + quad * 8);
    const bf16x8 qf1 = *(const bf16x8*)(qrow + quad * 8 + 32);

    // staging: thread covers 16B chunk (row rb+32i, chunk tid&7), XOR-swizzled
    const int rb   = tid >> 3;                    // 0..31
    const int cswz = (tid & 7) ^ (rb & 7);

    auto stage = [&](int b, int k0) {
        gload_lds16(Kh + ((long)(h * T_DIM + k0 + rb) << 6) + cswz * 8,
                    &sK[b][0] + tid * 8);
        gload_lds16(Kh + ((long)(h * T_DIM + k0 + rb + 32) << 6) + cswz * 8,
                    &sK[b][0] + 2048 + tid * 8);
        gload_lds16(Vth + ((long)(h * HD + rb) << 11) + k0 + cswz * 8,
                    &sV[b][0] + tid * 8);
        gload_lds16(Vth + ((long)(h * HD + rb + 32) << 11) + k0 + cswz * 8,
                    &sV[b][0] + 2048 + tid * 8);
    };

    stage(0, kt0 * 64);

    float l_i = 0.f;
    floatx4 o_acc[4];
#pragma unroll
    for (int d4 = 0; d4 < 4; d4++) o_acc[d4] = (floatx4){0.f, 0.f, 0.f, 0.f};

    for (int kt = kt0; kt < ktend; ++kt) {
        const int it = kt - kt0;
        __syncthreads();
        if (kt + 1 < ktend) stage((it + 1) & 1, (kt + 1) * 64);
        const bf16* K_ = &sK[it & 1][0];
        const bf16* V_ = &sV[it & 1][0];
        const int k0 = kt * 64;
        const bool diag = (kt == qt);

        // S^T: A=K rows, B=Q (in regs); lane owns q=lane&15, k=nt*16+quad*4+r
        // P kept in registers as K=16 MFMA A-operands pa[nt].
        short4v pa[4];
        float s = 0.f;
#pragma unroll
        for (int nt = 0; nt < 4; nt++) {
            const bf16* kr = K_ + (nt * 16 + fr) * 64;
            const bf16x8 ka0 = *(const bf16x8*)(kr + (quad ^ f7) * 8);
            const bf16x8 ka1 = *(const bf16x8*)(kr + ((quad + 4) ^ f7) * 8);
            floatx4 z = (floatx4){0.f, 0.f, 0.f, 0.f};
            z = MFMA16(ka0, qf0, z);
            z = MFMA16(ka1, qf1, z);
            const int kgb = k0 + nt * 16 + quad * 4;
            bf16x4 pk;
#pragma unroll
            for (int r = 0; r < 4; r++) {
                const float e = __builtin_amdgcn_exp2f(z[r] * 0.1803368801f);
                const float pv = (!diag || (kgb + r <= qg)) ? e : 0.f;
                s += pv;
                pk[r] = (bf16)pv;
            }
            pa[nt] = __builtin_bit_cast(short4v, pk);
        }
        // row sum: in-lane + 2 cross-quad shuffles
        s += __shfl_xor(s, 16);
        s += __shfl_xor(s, 32);
        l_i += s;

        // O += P.V (K=16): B[n=d][k=nt*16+quad*4+j] from V^T row d, b64 reads
#pragma unroll
        for (int d4 = 0; d4 < 4; d4++) {
            const bf16* vrow = V_ + (d4 * 16 + fr) * 64;
#pragma unroll
            for (int nt = 0; nt < 4; nt++) {
                const short4v vb = __builtin_bit_cast(short4v,
                    *(const bf16x4*)(vrow +
                        (((2 * nt + (quad >> 1)) ^ f7) * 8) + (quad & 1) * 4));
                o_acc[d4] = MFMAK16(pa[nt], vb, o_acc[d4]);
            }
        }
    }

    if (kt0 == 0 && ktend == nk) {
        // single-chunk q-tile: normalize and write YY directly
        const float inv_self = 1.f / l_i;
        float inv[4];
#pragma unroll
        for (int r = 0; r < 4; r++) inv[r] = __shfl(inv_self, quad * 4 + r);
#pragma unroll
        for (int r = 0; r < 4; r++) {
            const int q = q0 + wid * 16 + quad * 4 + r;
            const int rq = q >> 10, cq = q & 1023;
#pragma unroll
            for (int d4 = 0; d4 < 4; d4++) {
                const int d = d4 * 16 + fr;
                YY[(long)(h * 128 + 2 * d + rq) * 1024 + cq] =
                    (bf16)(o_acc[d4][r] * inv[r]);
            }
        }
    } else {
        // partial store: O (C-layout scatter, f32) + l (per q row)
        const long obase = ((long)((h * 32 + qt) * 4 + c)) * 4096;
#pragma unroll
        for (int d4 = 0; d4 < 4; d4++)
#pragma unroll
            for (int r = 0; r < 4; r++)
                Opart[obase + (wid * 16 + quad * 4 + r) * 64 + d4 * 16 + fr] =
                    o_acc[d4][r];
        if (quad == 0)
            lpart[((h * 32 + qt) * 4 + c) * 64 + wid * 16 + fr] = l_i;
    }
}

// ---------------------------------------------------------------------------
// Combine partials for qt >= 8: sum <=4 chunks, normalize, write YY.
// grid (24, 16): qt = blockIdx.x + 8. Thread owns 16 consecutive f32 of the
// 64x64 O tile (one quarter-row: fixed q, 16 d).
// ---------------------------------------------------------------------------
__global__ __launch_bounds__(256) void csa_combine(
    const float* __restrict__ Opart, const float* __restrict__ lpart,
    bf16* __restrict__ YY)
{
    const int qt = blockIdx.x + 8;
    const int h  = blockIdx.y;
    const int nc = (qt >> 3) + 1;               // 2..4
    const int t  = threadIdx.x;
    const int q  = t >> 2;                      // 0..63
    const int d0 = (t & 3) * 16;

    const long obase = ((long)((h * 32 + qt) * 4)) * 4096 + q * 64 + d0;
    const int  lbase = (h * 32 + qt) * 4 * 64 + q;

    float4 acc[4] = {};
    float lq = 0.f;
    for (int c = 0; c < nc; c++) {
        const float4* src = (const float4*)(Opart + obase + (long)c * 4096);
#pragma unroll
        for (int j = 0; j < 4; j++) {
            const float4 v = src[j];
            acc[j].x += v.x; acc[j].y += v.y; acc[j].z += v.z; acc[j].w += v.w;
        }
        lq += lpart[lbase + c * 64];
    }
    const float inv = 1.f / lq;
    const int qglob = qt * 64 + q;
    const int rq = qglob >> 10, cq = qglob & 1023;
#pragma unroll
    for (int j = 0; j < 4; j++) {
        const float vv[4] = {acc[j].x, acc[j].y, acc[j].z, acc[j].w};
#pragma unroll
        for (int k = 0; k < 4; k++) {
            const int d = d0 + j * 4 + k;
            YY[(long)(h * 128 + 2 * d + rq) * 1024 + cq] = (bf16)(vv[k] * inv);
        }
    }
}

extern "C" void kernel_launch(void* const* d_in, const int* in_sizes, int n_in,
                              void* d_out, int out_size, void* d_ws, size_t ws_size,
                              hipStream_t stream) {
    (void)in_sizes; (void)n_in; (void)out_size; (void)ws_size;
    const float* x      = (const float*)d_in[0];
    const float* w_attn = (const float*)d_in[1];
    const float* b_attn = (const float*)d_in[2];
    const float* w_proj = (const float*)d_in[3];
    const float* b_proj = (const float*)d_in[4];

    // workspace layout
    bf16* xb  = (bf16*)d_ws;                          // [T][C]
    bf16* wab = xb  + (size_t)T_DIM * C_DIM;          // [3C][C]
    bf16* wpb = wab + (size_t)3 * C_DIM * C_DIM;      // [C][C]
    bf16* Q   = wpb + (size_t)C_DIM * C_DIM;          // [NH][T][HD]
    bf16* Kp  = Q   + (size_t)NH * T_DIM * HD;        // [NH][T][HD]
    bf16* Vt  = Kp  + (size_t)NH * T_DIM * HD;        // [NH][HD][T]
    bf16* YY  = Vt  + (size_t)NH * T_DIM * HD;        // [T][C] permuted pre-proj
    float* Opart = (float*)(YY + (size_t)T_DIM * C_DIM);   // [16][32][4][64][64]
    float* lpart = Opart + (size_t)16 * 32 * 4 * 4096;     // [16][32][4][64]

    // fused f32->bf16 conversion (x, w_attn, w_proj)
    cvt_all<<<3072, 256, 0, stream>>>(x, w_attn, w_proj, xb, wab, wpb);

    // qkv projection: 128x64 tiles -> 768 blocks = 3/CU balanced
    csa_gemm_bt<0, 64><<<dim3(16, 48), 256, 0, stream>>>(xb, wab, b_attn, Q, Kp, Vt);
    // chunked causal flash attention (register-P, heavy-first) + combine
    csa_attn_chunk<<<dim3(4, NH, 32), 256, 0, stream>>>(Q, Kp, Vt, Opart, lpart, YY);
    csa_combine<<<dim3(24, NH), 256, 0, stream>>>(Opart, lpart, YY);
    // output projection: yy @ w_proj^T + b_proj -> f32 out
    csa_gemm_bt<1, 64><<<dim3(16, 16), 256, 0, stream>>>(YY, wpb, b_proj, d_out, nullptr, nullptr);
}

// Round 10
// 153.804 us; speedup vs baseline: 1.0894x; 1.0097x over previous
//
#include <hip/hip_runtime.h>
#include <hip/hip_bf16.h>
#include <stdint.h>

typedef __bf16 bf16;
typedef __bf16 bf16x8 __attribute__((ext_vector_type(8)));
typedef __bf16 bf16x4 __attribute__((ext_vector_type(4)));
typedef float floatx4 __attribute__((ext_vector_type(4)));
typedef short short4v __attribute__((ext_vector_type(4)));

#define T_DIM 2048
#define C_DIM 1024
#define NH    16
#define HD    64

__device__ __forceinline__ void gload_lds16(const void* g, void* l) {
    __builtin_amdgcn_global_load_lds(
        (__attribute__((address_space(1))) void*)(g),
        (__attribute__((address_space(3))) void*)(l),
        16, 0, 0);
}

#define MFMA16(a, b, c)  __builtin_amdgcn_mfma_f32_16x16x32_bf16(a, b, c, 0, 0, 0)
#define MFMAK16(a, b, c) __builtin_amdgcn_mfma_f32_16x16x16bf16_1k(a, b, c, 0, 0, 0)

// ---------------------------------------------------------------------------
// Fused f32 -> bf16 convert for x (2M), w_attn (3M), w_proj (1M); 8 elem/thread
// ---------------------------------------------------------------------------
__global__ __launch_bounds__(256) void cvt_all(
    const float* __restrict__ x, const float* __restrict__ wa,
    const float* __restrict__ wp,
    bf16* __restrict__ xb, bf16* __restrict__ wab, bf16* __restrict__ wpb)
{
    const int i = blockIdx.x * 256 + threadIdx.x;     // < 786432
    const float* src; bf16* dst; int off;
    if (i < 262144)      { src = x;  dst = xb;  off = i; }
    else if (i < 655360) { src = wa; dst = wab; off = i - 262144; }
    else                 { src = wp; dst = wpb; off = i - 655360; }
    const float4 a = ((const float4*)src)[off * 2];
    const float4 b = ((const float4*)src)[off * 2 + 1];
    bf16x8 o;
    o[0] = (bf16)a.x; o[1] = (bf16)a.y; o[2] = (bf16)a.z; o[3] = (bf16)a.w;
    o[4] = (bf16)b.x; o[5] = (bf16)b.y; o[6] = (bf16)b.z; o[7] = (bf16)b.w;
    *(bf16x8*)(dst + (size_t)off * 8) = o;
}

// ---------------------------------------------------------------------------
// NT GEMM: out[m,n] = sum_k A[m,k]*B[n,k] + bias[n].  A: Mx1024, B: Nx1024 bf16.
// BK=64, double-buffered LDS, ONE barrier per k-step (prefetch issued right
// after the barrier, latency hidden under compute). XOR-chunk swizzle
// (physical 16B chunk = logical ^ (row&7), swizzled on the GLOBAL side so the
// global_load_lds dest stays linear in lane) -> conflict-free b128 reads.
// TM=128,TN=64 (qkv, 4 waves stacked in M) or TM=64,TN=64 (proj, 2x2 waves).
// MODE 0: N=3072. Scatter Q->[h][t][d], K->[h][t][d], V->Vt[h][d][t].
// MODE 1: f32 row-major store (proj output).
// ---------------------------------------------------------------------------
template<int MODE, int TM, int TN>
__global__ __launch_bounds__(256) void csa_gemm_bt(
    const bf16* __restrict__ A, const bf16* __restrict__ B,
    const float* __restrict__ bias,
    void* __restrict__ out0v, bf16* __restrict__ out1, bf16* __restrict__ out2)
{
    constexpr int K   = 1024;
    constexpr int WM  = (TM == 128) ? 4 : 2;     // waves in M
    constexpr int WN  = 4 / WM;                  // waves in N
    constexpr int MT  = 2;                       // 16-row subtiles per wave
    constexpr int NT  = TN / (16 * WN);          // 4 (qkv) / 2 (proj)
    constexpr int ACH = TM / 32;                 // A 16B-chunks per thread
    constexpr int BCH = TN / 32;                 // B 16B-chunks per thread
    __shared__ __align__(16) bf16 sA[2][TM * 64];
    __shared__ __align__(16) bf16 sB[2][TN * 64];

    const int tid  = threadIdx.x;
    const int lane = tid & 63;
    const int wid  = tid >> 6;
    const int wm   = wid & (WM - 1);
    const int wn   = wid / WM;
    const int rowbase = wm * 32;
    const int colbase = wn * (TN / WN);
    const int tileM = blockIdx.x * TM;
    const int tileN = blockIdx.y * TN;

    const int fr   = lane & 15;
    const int quad = lane >> 4;
    const int f7   = fr & 7;

    auto stage = [&](int b, int k0) {
#pragma unroll
        for (int i = 0; i < ACH; i++) {
            const int cid = tid + 256 * i;
            const int row = cid >> 3, pc = cid & 7;
            gload_lds16(A + (long)(tileM + row) * K + k0 + (pc ^ (row & 7)) * 8,
                        &sA[b][0] + cid * 8);
        }
#pragma unroll
        for (int i = 0; i < BCH; i++) {
            const int cid = tid + 256 * i;
            const int row = cid >> 3, pc = cid & 7;
            gload_lds16(B + (long)(tileN + row) * K + k0 + (pc ^ (row & 7)) * 8,
                        &sB[b][0] + cid * 8);
        }
    };

    floatx4 acc[MT][NT];
#pragma unroll
    for (int i = 0; i < MT; i++)
#pragma unroll
        for (int j = 0; j < NT; j++) acc[i][j] = (floatx4){0.f, 0.f, 0.f, 0.f};

    stage(0, 0);

    for (int it = 0; it < K / 64; ++it) {
        __syncthreads();
        if (it + 1 < K / 64) stage((it + 1) & 1, (it + 1) * 64);
        const bf16* A_ = &sA[it & 1][0];
        const bf16* B_ = &sB[it & 1][0];

        bf16x8 af[MT][2], bfr[NT][2];
#pragma unroll
        for (int mt = 0; mt < MT; mt++) {
            const int row = rowbase + mt * 16 + fr;
#pragma unroll
            for (int kh = 0; kh < 2; kh++)
                af[mt][kh] = *(const bf16x8*)(A_ + row * 64 +
                                              ((kh * 4 + quad) ^ f7) * 8);
        }
#pragma unroll
        for (int nt = 0; nt < NT; nt++) {
            const int row = colbase + nt * 16 + fr;
#pragma unroll
            for (int kh = 0; kh < 2; kh++)
                bfr[nt][kh] = *(const bf16x8*)(B_ + row * 64 +
                                               ((kh * 4 + quad) ^ f7) * 8);
        }
#pragma unroll
        for (int mt = 0; mt < MT; mt++)
#pragma unroll
            for (int nt = 0; nt < NT; nt++) {
                acc[mt][nt] = MFMA16(af[mt][0], bfr[nt][0], acc[mt][nt]);
                acc[mt][nt] = MFMA16(af[mt][1], bfr[nt][1], acc[mt][nt]);
            }
    }

    // epilogue: C/D layout col = lane&15, row = quad*4 + reg
#pragma unroll
    for (int mt = 0; mt < MT; mt++) {
#pragma unroll
        for (int nt = 0; nt < NT; nt++) {
            const int gn = tileN + colbase + nt * 16 + fr;
            const float bv = bias[gn];
            const int gmb = tileM + rowbase + mt * 16 + quad * 4;
            if (MODE == 0) {
                const int which = gn >> 10;
                const int w2 = gn & 1023;
                const int hh = w2 >> 6, d = w2 & 63;
                if (which == 2) {
                    bf16x4 pk;
#pragma unroll
                    for (int r = 0; r < 4; r++) pk[r] = (bf16)(acc[mt][nt][r] + bv);
                    *(bf16x4*)(out2 + ((long)(hh * HD + d) << 11) + gmb) = pk;
                } else {
                    bf16* dst = (which == 0) ? (bf16*)out0v : out1;
#pragma unroll
                    for (int r = 0; r < 4; r++)
                        dst[((long)hh * T_DIM + gmb + r) * HD + d] =
                            (bf16)(acc[mt][nt][r] + bv);
                }
            } else {
#pragma unroll
                for (int r = 0; r < 4; r++)
                    ((float*)out0v)[(long)(gmb + r) * C_DIM + gn] =
                        acc[mt][nt][r] + bv;
            }
        }
    }
}

// ---------------------------------------------------------------------------
// Chunked causal flash attention (no-max softmax -> partials ADDITIVE).
// grid (c=4, h=16, z=32); qt = 31 - z so heaviest chunks dispatch FIRST.
// Chunk c covers k-tiles [8c, min(8c+8, qt+1)). Wave owns 16 q-rows, all k.
// P stays in REGISTERS (S^T C-layout == K=16 MFMA A-layout).
// ---------------------------------------------------------------------------
__global__ __launch_bounds__(256) void csa_attn_chunk(
    const bf16* __restrict__ Qh, const bf16* __restrict__ Kh,
    const bf16* __restrict__ Vth, float* __restrict__ Opart,
    float* __restrict__ lpart, bf16* __restrict__ YY)
{
    __shared__ __align__(16) bf16 sK[2][64 * 64];
    __shared__ __align__(16) bf16 sV[2][64 * 64];

    const int c  = blockIdx.x;
    const int h  = blockIdx.y;
    const int qt = 31 - (int)blockIdx.z;         // heavy q-tiles first
    const int nk = qt + 1;
    const int kt0 = c * 8;
    if (kt0 >= nk) return;                       // invalid chunk
    const int ktend = (kt0 + 8 < nk) ? kt0 + 8 : nk;

    const int tid  = threadIdx.x;
    const int lane = tid & 63;
    const int wid  = tid >> 6;
    const int fr   = lane & 15;
    const int quad = lane >> 4;
    const int f7   = fr & 7;
    const int q0   = qt * 64;
    const int qg   = q0 + wid * 16 + fr;

    // Q B-fragments: B[n=lane&15=q][k=quad*8+j] = Q[qg][d]
    const bf16* qrow = Qh + ((long)h * T_DIM + qg) * HD;
    const bf16x8 qf0 = *(const bf16x8*)(qrow + quad * 8);
    const bf16x8 qf1 = *(const bf16x8*)(qrow + quad * 8 + 32);

    // staging: thread covers 16B chunk (row rb+32i, chunk tid&7), XOR-swizzled
    const int rb   = tid >> 3;                    // 0..31
    const int cswz = (tid & 7) ^ (rb & 7);

    auto stage = [&](int b, int k0) {
        gload_lds16(Kh + ((long)(h * T_DIM + k0 + rb) << 6) + cswz * 8,
                    &sK[b][0] + tid * 8);
        gload_lds16(Kh + ((long)(h * T_DIM + k0 + rb + 32) << 6) + cswz * 8,
                    &sK[b][0] + 2048 + tid * 8);
        gload_lds16(Vth + ((long)(h * HD + rb) << 11) + k0 + cswz * 8,
                    &sV[b][0] + tid * 8);
        gload_lds16(Vth + ((long)(h * HD + rb + 32) << 11) + k0 + cswz * 8,
                    &sV[b][0] + 2048 + tid * 8);
    };

    stage(0, kt0 * 64);

    float l_i = 0.f;
    floatx4 o_acc[4];
#pragma unroll
    for (int d4 = 0; d4 < 4; d4++) o_acc[d4] = (floatx4){0.f, 0.f, 0.f, 0.f};

    for (int kt = kt0; kt < ktend; ++kt) {
        const int it = kt - kt0;
        __syncthreads();
        if (kt + 1 < ktend) stage((it + 1) & 1, (kt + 1) * 64);
        const bf16* K_ = &sK[it & 1][0];
        const bf16* V_ = &sV[it & 1][0];
        const int k0 = kt * 64;
        const bool diag = (kt == qt);

        // S^T: A=K rows, B=Q (in regs); lane owns q=lane&15, k=nt*16+quad*4+r
        short4v pa[4];
        float s = 0.f;
#pragma unroll
        for (int nt = 0; nt < 4; nt++) {
            const bf16* kr = K_ + (nt * 16 + fr) * 64;
            const bf16x8 ka0 = *(const bf16x8*)(kr + (quad ^ f7) * 8);
            const bf16x8 ka1 = *(const bf16x8*)(kr + ((quad + 4) ^ f7) * 8);
            floatx4 z = (floatx4){0.f, 0.f, 0.f, 0.f};
            z = MFMA16(ka0, qf0, z);
            z = MFMA16(ka1, qf1, z);
            const int kgb = k0 + nt * 16 + quad * 4;
            bf16x4 pk;
#pragma unroll
            for (int r = 0; r < 4; r++) {
                const float e = __builtin_amdgcn_exp2f(z[r] * 0.1803368801f);
                const float pv = (!diag || (kgb + r <= qg)) ? e : 0.f;
                s += pv;
                pk[r] = (bf16)pv;
            }
            pa[nt] = __builtin_bit_cast(short4v, pk);
        }
        // row sum: in-lane + 2 cross-quad shuffles
        s += __shfl_xor(s, 16);
        s += __shfl_xor(s, 32);
        l_i += s;

        // O += P.V (K=16): B[n=d][k=nt*16+quad*4+j] from V^T row d, b64 reads
#pragma unroll
        for (int d4 = 0; d4 < 4; d4++) {
            const bf16* vrow = V_ + (d4 * 16 + fr) * 64;
#pragma unroll
            for (int nt = 0; nt < 4; nt++) {
                const short4v vb = __builtin_bit_cast(short4v,
                    *(const bf16x4*)(vrow +
                        (((2 * nt + (quad >> 1)) ^ f7) * 8) + (quad & 1) * 4));
                o_acc[d4] = MFMAK16(pa[nt], vb, o_acc[d4]);
            }
        }
    }

    if (kt0 == 0 && ktend == nk) {
        // single-chunk q-tile: normalize and write YY directly
        const float inv_self = 1.f / l_i;
        float inv[4];
#pragma unroll
        for (int r = 0; r < 4; r++) inv[r] = __shfl(inv_self, quad * 4 + r);
#pragma unroll
        for (int r = 0; r < 4; r++) {
            const int q = q0 + wid * 16 + quad * 4 + r;
            const int rq = q >> 10, cq = q & 1023;
#pragma unroll
            for (int d4 = 0; d4 < 4; d4++) {
                const int d = d4 * 16 + fr;
                YY[(long)(h * 128 + 2 * d + rq) * 1024 + cq] =
                    (bf16)(o_acc[d4][r] * inv[r]);
            }
        }
    } else {
        // partial store: O (C-layout scatter, f32) + l (per q row)
        const long obase = ((long)((h * 32 + qt) * 4 + c)) * 4096;
#pragma unroll
        for (int d4 = 0; d4 < 4; d4++)
#pragma unroll
            for (int r = 0; r < 4; r++)
                Opart[obase + (wid * 16 + quad * 4 + r) * 64 + d4 * 16 + fr] =
                    o_acc[d4][r];
        if (quad == 0)
            lpart[((h * 32 + qt) * 4 + c) * 64 + wid * 16 + fr] = l_i;
    }
}

// ---------------------------------------------------------------------------
// Combine partials for qt >= 8: sum <=4 chunks, normalize, write YY.
// grid (24, 16): qt = blockIdx.x + 8.
// ---------------------------------------------------------------------------
__global__ __launch_bounds__(256) void csa_combine(
    const float* __restrict__ Opart, const float* __restrict__ lpart,
    bf16* __restrict__ YY)
{
    const int qt = blockIdx.x + 8;
    const int h  = blockIdx.y;
    const int nc = (qt >> 3) + 1;               // 2..4
    const int t  = threadIdx.x;
    const int q  = t >> 2;                      // 0..63
    const int d0 = (t & 3) * 16;

    const long obase = ((long)((h * 32 + qt) * 4)) * 4096 + q * 64 + d0;
    const int  lbase = (h * 32 + qt) * 4 * 64 + q;

    float4 acc[4] = {};
    float lq = 0.f;
    for (int c = 0; c < nc; c++) {
        const float4* src = (const float4*)(Opart + obase + (long)c * 4096);
#pragma unroll
        for (int j = 0; j < 4; j++) {
            const float4 v = src[j];
            acc[j].x += v.x; acc[j].y += v.y; acc[j].z += v.z; acc[j].w += v.w;
        }
        lq += lpart[lbase + c * 64];
    }
    const float inv = 1.f / lq;
    const int qglob = qt * 64 + q;
    const int rq = qglob >> 10, cq = qglob & 1023;
#pragma unroll
    for (int j = 0; j < 4; j++) {
        const float vv[4] = {acc[j].x, acc[j].y, acc[j].z, acc[j].w};
#pragma unroll
        for (int k = 0; k < 4; k++) {
            const int d = d0 + j * 4 + k;
            YY[(long)(h * 128 + 2 * d + rq) * 1024 + cq] = (bf16)(vv[k] * inv);
        }
    }
}

extern "C" void kernel_launch(void* const* d_in, const int* in_sizes, int n_in,
                              void* d_out, int out_size, void* d_ws, size_t ws_size,
                              hipStream_t stream) {
    (void)in_sizes; (void)n_in; (void)out_size; (void)ws_size;
    const float* x      = (const float*)d_in[0];
    const float* w_attn = (const float*)d_in[1];
    const float* b_attn = (const float*)d_in[2];
    const float* w_proj = (const float*)d_in[3];
    const float* b_proj = (const float*)d_in[4];

    // workspace layout
    bf16* xb  = (bf16*)d_ws;                          // [T][C]
    bf16* wab = xb  + (size_t)T_DIM * C_DIM;          // [3C][C]
    bf16* wpb = wab + (size_t)3 * C_DIM * C_DIM;      // [C][C]
    bf16* Q   = wpb + (size_t)C_DIM * C_DIM;          // [NH][T][HD]
    bf16* Kp  = Q   + (size_t)NH * T_DIM * HD;        // [NH][T][HD]
    bf16* Vt  = Kp  + (size_t)NH * T_DIM * HD;        // [NH][HD][T]
    bf16* YY  = Vt  + (size_t)NH * T_DIM * HD;        // [T][C] permuted pre-proj
    float* Opart = (float*)(YY + (size_t)T_DIM * C_DIM);   // [16][32][4][64][64]
    float* lpart = Opart + (size_t)16 * 32 * 4 * 4096;     // [16][32][4][64]

    // fused f32->bf16 conversion (x, w_attn, w_proj)
    cvt_all<<<3072, 256, 0, stream>>>(x, w_attn, w_proj, xb, wab, wpb);

    // qkv projection: 128x64 tiles, BK=64 dbuf, 768 blocks = 3/CU
    csa_gemm_bt<0, 128, 64><<<dim3(16, 48), 256, 0, stream>>>(xb, wab, b_attn, Q, Kp, Vt);
    // chunked causal flash attention (register-P, heavy-first) + combine
    csa_attn_chunk<<<dim3(4, NH, 32), 256, 0, stream>>>(Q, Kp, Vt, Opart, lpart, YY);
    csa_combine<<<dim3(24, NH), 256, 0, stream>>>(Opart, lpart, YY);
    // output projection: 64x64 tiles, BK=64 dbuf, 512 blocks = 2/CU
    csa_gemm_bt<1, 64, 64><<<dim3(32, 16), 256, 0, stream>>>(YY, wpb, b_proj, d_out, nullptr, nullptr);
}

// Round 11
// 153.570 us; speedup vs baseline: 1.0911x; 1.0015x over previous
//
#include <hip/hip_runtime.h>
#include <hip/hip_bf16.h>
#include <stdint.h>

typedef __bf16 bf16;
typedef __bf16 bf16x8 __attribute__((ext_vector_type(8)));
typedef __bf16 bf16x4 __attribute__((ext_vector_type(4)));
typedef float floatx4 __attribute__((ext_vector_type(4)));

#define T_DIM 2048
#define C_DIM 1024
#define NH    16
#define HD    64

__device__ __forceinline__ void gload_lds16(const void* g, void* l) {
    __builtin_amdgcn_global_load_lds(
        (__attribute__((address_space(1))) void*)(g),
        (__attribute__((address_space(3))) void*)(l),
        16, 0, 0);
}

#define MFMA16(a, b, c)  __builtin_amdgcn_mfma_f32_16x16x32_bf16(a, b, c, 0, 0, 0)

// ---------------------------------------------------------------------------
// Fused f32 -> bf16 convert for x (2M), w_attn (3M), w_proj (1M); 8 elem/thread
// ---------------------------------------------------------------------------
__global__ __launch_bounds__(256) void cvt_all(
    const float* __restrict__ x, const float* __restrict__ wa,
    const float* __restrict__ wp,
    bf16* __restrict__ xb, bf16* __restrict__ wab, bf16* __restrict__ wpb)
{
    const int i = blockIdx.x * 256 + threadIdx.x;     // < 786432
    const float* src; bf16* dst; int off;
    if (i < 262144)      { src = x;  dst = xb;  off = i; }
    else if (i < 655360) { src = wa; dst = wab; off = i - 262144; }
    else                 { src = wp; dst = wpb; off = i - 655360; }
    const float4 a = ((const float4*)src)[off * 2];
    const float4 b = ((const float4*)src)[off * 2 + 1];
    bf16x8 o;
    o[0] = (bf16)a.x; o[1] = (bf16)a.y; o[2] = (bf16)a.z; o[3] = (bf16)a.w;
    o[4] = (bf16)b.x; o[5] = (bf16)b.y; o[6] = (bf16)b.z; o[7] = (bf16)b.w;
    *(bf16x8*)(dst + (size_t)off * 8) = o;
}

// ---------------------------------------------------------------------------
// NT GEMM: out[m,n] = sum_k A[m,k]*B[n,k] + bias[n].  A: Mx1024, B: Nx1024 bf16.
// BK=64, double-buffered LDS, ONE barrier per k-step (prefetch issued right
// after the barrier). XOR-chunk swizzle on the GLOBAL side -> conflict-free
// b128 LDS reads.  TM=128/TN=64 (qkv) or TM=64/TN=64 (proj).
// MODE 0: N=3072. Scatter Q->[h][t][d], K->[h][t][d], V->Vt[h][d][t].
// MODE 1: f32 row-major store (proj output).
// ---------------------------------------------------------------------------
template<int MODE, int TM, int TN>
__global__ __launch_bounds__(256) void csa_gemm_bt(
    const bf16* __restrict__ A, const bf16* __restrict__ B,
    const float* __restrict__ bias,
    void* __restrict__ out0v, bf16* __restrict__ out1, bf16* __restrict__ out2)
{
    constexpr int K   = 1024;
    constexpr int WM  = (TM == 128) ? 4 : 2;     // waves in M
    constexpr int WN  = 4 / WM;                  // waves in N
    constexpr int MT  = 2;                       // 16-row subtiles per wave
    constexpr int NT  = TN / (16 * WN);          // 4 (qkv) / 2 (proj)
    constexpr int ACH = TM / 32;                 // A 16B-chunks per thread
    constexpr int BCH = TN / 32;                 // B 16B-chunks per thread
    __shared__ __align__(16) bf16 sA[2][TM * 64];
    __shared__ __align__(16) bf16 sB[2][TN * 64];

    const int tid  = threadIdx.x;
    const int lane = tid & 63;
    const int wid  = tid >> 6;
    const int wm   = wid & (WM - 1);
    const int wn   = wid / WM;
    const int rowbase = wm * 32;
    const int colbase = wn * (TN / WN);
    const int tileM = blockIdx.x * TM;
    const int tileN = blockIdx.y * TN;

    const int fr   = lane & 15;
    const int quad = lane >> 4;
    const int f7   = fr & 7;

    auto stage = [&](int b, int k0) {
#pragma unroll
        for (int i = 0; i < ACH; i++) {
            const int cid = tid + 256 * i;
            const int row = cid >> 3, pc = cid & 7;
            gload_lds16(A + (long)(tileM + row) * K + k0 + (pc ^ (row & 7)) * 8,
                        &sA[b][0] + cid * 8);
        }
#pragma unroll
        for (int i = 0; i < BCH; i++) {
            const int cid = tid + 256 * i;
            const int row = cid >> 3, pc = cid & 7;
            gload_lds16(B + (long)(tileN + row) * K + k0 + (pc ^ (row & 7)) * 8,
                        &sB[b][0] + cid * 8);
        }
    };

    floatx4 acc[MT][NT];
#pragma unroll
    for (int i = 0; i < MT; i++)
#pragma unroll
        for (int j = 0; j < NT; j++) acc[i][j] = (floatx4){0.f, 0.f, 0.f, 0.f};

    stage(0, 0);

    for (int it = 0; it < K / 64; ++it) {
        __syncthreads();
        if (it + 1 < K / 64) stage((it + 1) & 1, (it + 1) * 64);
        const bf16* A_ = &sA[it & 1][0];
        const bf16* B_ = &sB[it & 1][0];

        bf16x8 af[MT][2], bfr[NT][2];
#pragma unroll
        for (int mt = 0; mt < MT; mt++) {
            const int row = rowbase + mt * 16 + fr;
#pragma unroll
            for (int kh = 0; kh < 2; kh++)
                af[mt][kh] = *(const bf16x8*)(A_ + row * 64 +
                                              ((kh * 4 + quad) ^ f7) * 8);
        }
#pragma unroll
        for (int nt = 0; nt < NT; nt++) {
            const int row = colbase + nt * 16 + fr;
#pragma unroll
            for (int kh = 0; kh < 2; kh++)
                bfr[nt][kh] = *(const bf16x8*)(B_ + row * 64 +
                                               ((kh * 4 + quad) ^ f7) * 8);
        }
#pragma unroll
        for (int mt = 0; mt < MT; mt++)
#pragma unroll
            for (int nt = 0; nt < NT; nt++) {
                acc[mt][nt] = MFMA16(af[mt][0], bfr[nt][0], acc[mt][nt]);
                acc[mt][nt] = MFMA16(af[mt][1], bfr[nt][1], acc[mt][nt]);
            }
    }

    // epilogue: C/D layout col = lane&15, row = quad*4 + reg
#pragma unroll
    for (int mt = 0; mt < MT; mt++) {
#pragma unroll
        for (int nt = 0; nt < NT; nt++) {
            const int gn = tileN + colbase + nt * 16 + fr;
            const float bv = bias[gn];
            const int gmb = tileM + rowbase + mt * 16 + quad * 4;
            if (MODE == 0) {
                const int which = gn >> 10;
                const int w2 = gn & 1023;
                const int hh = w2 >> 6, d = w2 & 63;
                if (which == 2) {
                    bf16x4 pk;
#pragma unroll
                    for (int r = 0; r < 4; r++) pk[r] = (bf16)(acc[mt][nt][r] + bv);
                    *(bf16x4*)(out2 + ((long)(hh * HD + d) << 11) + gmb) = pk;
                } else {
                    bf16* dst = (which == 0) ? (bf16*)out0v : out1;
#pragma unroll
                    for (int r = 0; r < 4; r++)
                        dst[((long)hh * T_DIM + gmb + r) * HD + d] =
                            (bf16)(acc[mt][nt][r] + bv);
                }
            } else {
#pragma unroll
                for (int r = 0; r < 4; r++)
                    ((float*)out0v)[(long)(gmb + r) * C_DIM + gn] =
                        acc[mt][nt][r] + bv;
            }
        }
    }
}

// ---------------------------------------------------------------------------
// Chunked causal flash attention (no-max softmax -> partials ADDITIVE).
// grid (c=4, h=16, z=32); qt = 31 - z so heaviest chunks dispatch FIRST.
// Chunk c covers k-tiles [8c, min(8c+8, qt+1)). Wave owns 16 q-rows, all k.
// P via per-wave LDS round-trip (C-layout -> K=32 A-layout); r7-validated:
// beats register-P K=16 by ~3 us (fewer MFMA issues + b128 reads).
// ---------------------------------------------------------------------------
__global__ __launch_bounds__(256) void csa_attn_chunk(
    const bf16* __restrict__ Qh, const bf16* __restrict__ Kh,
    const bf16* __restrict__ Vth, float* __restrict__ Opart,
    float* __restrict__ lpart, bf16* __restrict__ YY)
{
    __shared__ __align__(16) bf16 sK[2][64 * 64];
    __shared__ __align__(16) bf16 sV[2][64 * 64];
    __shared__ __align__(16) bf16 sP[4][16 * 64];

    const int c  = blockIdx.x;
    const int h  = blockIdx.y;
    const int qt = 31 - (int)blockIdx.z;         // heavy q-tiles first
    const int nk = qt + 1;
    const int kt0 = c * 8;
    if (kt0 >= nk) return;                       // invalid chunk
    const int ktend = (kt0 + 8 < nk) ? kt0 + 8 : nk;

    const int tid  = threadIdx.x;
    const int lane = tid & 63;
    const int wid  = tid >> 6;
    const int fr   = lane & 15;
    const int quad = lane >> 4;
    const int f7   = fr & 7;
    const int q0   = qt * 64;
    const int qg   = q0 + wid * 16 + fr;

    // Q B-fragments: B[n=lane&15=q][k=quad*8+j] = Q[qg][d]
    const bf16* qrow = Qh + ((long)h * T_DIM + qg) * HD;
    const bf16x8 qf0 = *(const bf16x8*)(qrow + quad * 8);
    const bf16x8 qf1 = *(const bf16x8*)(qrow + quad * 8 + 32);

    // staging: thread covers 16B chunk (row rb+32i, chunk tid&7), XOR-swizzled
    const int rb   = tid >> 3;                    // 0..31
    const int cswz = (tid & 7) ^ (rb & 7);

    auto stage = [&](int b, int k0) {
        gload_lds16(Kh + ((long)(h * T_DIM + k0 + rb) << 6) + cswz * 8,
                    &sK[b][0] + tid * 8);
        gload_lds16(Kh + ((long)(h * T_DIM + k0 + rb + 32) << 6) + cswz * 8,
                    &sK[b][0] + 2048 + tid * 8);
        gload_lds16(Vth + ((long)(h * HD + rb) << 11) + k0 + cswz * 8,
                    &sV[b][0] + tid * 8);
        gload_lds16(Vth + ((long)(h * HD + rb + 32) << 11) + k0 + cswz * 8,
                    &sV[b][0] + 2048 + tid * 8);
    };

    stage(0, kt0 * 64);

    float l_i = 0.f;
    floatx4 o_acc[4];
#pragma unroll
    for (int d4 = 0; d4 < 4; d4++) o_acc[d4] = (floatx4){0.f, 0.f, 0.f, 0.f};

    for (int kt = kt0; kt < ktend; ++kt) {
        const int it = kt - kt0;
        __syncthreads();
        if (kt + 1 < ktend) stage((it + 1) & 1, (kt + 1) * 64);
        const bf16* K_ = &sK[it & 1][0];
        const bf16* V_ = &sV[it & 1][0];
        const int k0 = kt * 64;
        const bool diag = (kt == qt);

        // S^T: A=K rows, B=Q (in regs); lane owns q=lane&15, k=nt*16+quad*4+r
        float p[4][4];
#pragma unroll
        for (int nt = 0; nt < 4; nt++) {
            const bf16* kr = K_ + (nt * 16 + fr) * 64;
            const bf16x8 ka0 = *(const bf16x8*)(kr + (quad ^ f7) * 8);
            const bf16x8 ka1 = *(const bf16x8*)(kr + ((quad + 4) ^ f7) * 8);
            floatx4 z = (floatx4){0.f, 0.f, 0.f, 0.f};
            z = MFMA16(ka0, qf0, z);
            z = MFMA16(ka1, qf1, z);
            const int kgb = k0 + nt * 16 + quad * 4;
#pragma unroll
            for (int r = 0; r < 4; r++) {
                const float e = __builtin_amdgcn_exp2f(z[r] * 0.1803368801f);
                p[nt][r] = (!diag || (kgb + r <= qg)) ? e : 0.f;
            }
        }

        // row sum: in-lane + 2 cross-quad shuffles
        float s = 0.f;
#pragma unroll
        for (int nt = 0; nt < 4; nt++)
#pragma unroll
            for (int r = 0; r < 4; r++) s += p[nt][r];
        s += __shfl_xor(s, 16);
        s += __shfl_xor(s, 32);
        l_i += s;

        // P -> per-wave LDS, A-layout rows, XOR-swizzled, packed b64 writes
        bf16* pw = &sP[wid][0];
#pragma unroll
        for (int nt = 0; nt < 4; nt++) {
            bf16x4 pk;
#pragma unroll
            for (int r = 0; r < 4; r++) pk[r] = (bf16)p[nt][r];
            *(bf16x4*)(pw + fr * 64 +
                       (((2 * nt + (quad >> 1)) ^ f7) * 8) + (quad & 1) * 4) = pk;
        }
        asm volatile("s_waitcnt lgkmcnt(0)" ::: "memory");
        const bf16x8 pa0 = *(const bf16x8*)(pw + fr * 64 + (quad ^ f7) * 8);
        const bf16x8 pa1 = *(const bf16x8*)(pw + fr * 64 + ((quad + 4) ^ f7) * 8);

        // O += P.V : B[n=d][k=t] from V^T rows
#pragma unroll
        for (int d4 = 0; d4 < 4; d4++) {
            const bf16* vr = V_ + (d4 * 16 + fr) * 64;
            const bf16x8 vb0 = *(const bf16x8*)(vr + (quad ^ f7) * 8);
            const bf16x8 vb1 = *(const bf16x8*)(vr + ((quad + 4) ^ f7) * 8);
            o_acc[d4] = MFMA16(pa0, vb0, o_acc[d4]);
            o_acc[d4] = MFMA16(pa1, vb1, o_acc[d4]);
        }
    }

    if (kt0 == 0 && ktend == nk) {
        // single-chunk q-tile: normalize and write YY directly
        const float inv_self = 1.f / l_i;
        float inv[4];
#pragma unroll
        for (int r = 0; r < 4; r++) inv[r] = __shfl(inv_self, quad * 4 + r);
#pragma unroll
        for (int r = 0; r < 4; r++) {
            const int q = q0 + wid * 16 + quad * 4 + r;
            const int rq = q >> 10, cq = q & 1023;
#pragma unroll
            for (int d4 = 0; d4 < 4; d4++) {
                const int d = d4 * 16 + fr;
                YY[(long)(h * 128 + 2 * d + rq) * 1024 + cq] =
                    (bf16)(o_acc[d4][r] * inv[r]);
            }
        }
    } else {
        // partial store: O (C-layout scatter, f32) + l (per q row)
        const long obase = ((long)((h * 32 + qt) * 4 + c)) * 4096;
#pragma unroll
        for (int d4 = 0; d4 < 4; d4++)
#pragma unroll
            for (int r = 0; r < 4; r++)
                Opart[obase + (wid * 16 + quad * 4 + r) * 64 + d4 * 16 + fr] =
                    o_acc[d4][r];
        if (quad == 0)
            lpart[((h * 32 + qt) * 4 + c) * 64 + wid * 16 + fr] = l_i;
    }
}

// ---------------------------------------------------------------------------
// Combine partials for qt >= 8: sum <=4 chunks, normalize, write YY.
// grid (24, 16): qt = blockIdx.x + 8.
// ---------------------------------------------------------------------------
__global__ __launch_bounds__(256) void csa_combine(
    const float* __restrict__ Opart, const float* __restrict__ lpart,
    bf16* __restrict__ YY)
{
    const int qt = blockIdx.x + 8;
    const int h  = blockIdx.y;
    const int nc = (qt >> 3) + 1;               // 2..4
    const int t  = threadIdx.x;
    const int q  = t >> 2;                      // 0..63
    const int d0 = (t & 3) * 16;

    const long obase = ((long)((h * 32 + qt) * 4)) * 4096 + q * 64 + d0;
    const int  lbase = (h * 32 + qt) * 4 * 64 + q;

    float4 acc[4] = {};
    float lq = 0.f;
    for (int c = 0; c < nc; c++) {
        const float4* src = (const float4*)(Opart + obase + (long)c * 4096);
#pragma unroll
        for (int j = 0; j < 4; j++) {
            const float4 v = src[j];
            acc[j].x += v.x; acc[j].y += v.y; acc[j].z += v.z; acc[j].w += v.w;
        }
        lq += lpart[lbase + c * 64];
    }
    const float inv = 1.f / lq;
    const int qglob = qt * 64 + q;
    const int rq = qglob >> 10, cq = qglob & 1023;
#pragma unroll
    for (int j = 0; j < 4; j++) {
        const float vv[4] = {acc[j].x, acc[j].y, acc[j].z, acc[j].w};
#pragma unroll
        for (int k = 0; k < 4; k++) {
            const int d = d0 + j * 4 + k;
            YY[(long)(h * 128 + 2 * d + rq) * 1024 + cq] = (bf16)(vv[k] * inv);
        }
    }
}

extern "C" void kernel_launch(void* const* d_in, const int* in_sizes, int n_in,
                              void* d_out, int out_size, void* d_ws, size_t ws_size,
                              hipStream_t stream) {
    (void)in_sizes; (void)n_in; (void)out_size; (void)ws_size;
    const float* x      = (const float*)d_in[0];
    const float* w_attn = (const float*)d_in[1];
    const float* b_attn = (const float*)d_in[2];
    const float* w_proj = (const float*)d_in[3];
    const float* b_proj = (const float*)d_in[4];

    // workspace layout
    bf16* xb  = (bf16*)d_ws;                          // [T][C]
    bf16* wab = xb  + (size_t)T_DIM * C_DIM;          // [3C][C]
    bf16* wpb = wab + (size_t)3 * C_DIM * C_DIM;      // [C][C]
    bf16* Q   = wpb + (size_t)C_DIM * C_DIM;          // [NH][T][HD]
    bf16* Kp  = Q   + (size_t)NH * T_DIM * HD;        // [NH][T][HD]
    bf16* Vt  = Kp  + (size_t)NH * T_DIM * HD;        // [NH][HD][T]
    bf16* YY  = Vt  + (size_t)NH * T_DIM * HD;        // [T][C] permuted pre-proj
    float* Opart = (float*)(YY + (size_t)T_DIM * C_DIM);   // [16][32][4][64][64]
    float* lpart = Opart + (size_t)16 * 32 * 4 * 4096;     // [16][32][4][64]

    // fused f32->bf16 conversion (x, w_attn, w_proj)
    cvt_all<<<3072, 256, 0, stream>>>(x, w_attn, w_proj, xb, wab, wpb);

    // qkv projection: 128x64 tiles, BK=64 dbuf, 768 blocks = 3/CU
    csa_gemm_bt<0, 128, 64><<<dim3(16, 48), 256, 0, stream>>>(xb, wab, b_attn, Q, Kp, Vt);
    // chunked causal flash attention (LDS-P, heavy-first) + combine
    csa_attn_chunk<<<dim3(4, NH, 32), 256, 0, stream>>>(Q, Kp, Vt, Opart, lpart, YY);
    csa_combine<<<dim3(24, NH), 256, 0, stream>>>(Opart, lpart, YY);
    // output projection: 64x64 tiles, BK=64 dbuf, 512 blocks = 2/CU
    csa_gemm_bt<1, 64, 64><<<dim3(32, 16), 256, 0, stream>>>(YY, wpb, b_proj, d_out, nullptr, nullptr);
}

// Round 12
// 146.179 us; speedup vs baseline: 1.1463x; 1.0506x over previous
//
#include <hip/hip_runtime.h>
#include <hip/hip_bf16.h>
#include <stdint.h>

typedef __bf16 bf16;
typedef __bf16 bf16x8 __attribute__((ext_vector_type(8)));
typedef __bf16 bf16x4 __attribute__((ext_vector_type(4)));
typedef float floatx4 __attribute__((ext_vector_type(4)));

#define T_DIM 2048
#define C_DIM 1024
#define NH    16
#define HD    64

__device__ __forceinline__ void gload_lds16(const void* g, void* l) {
    __builtin_amdgcn_global_load_lds(
        (__attribute__((address_space(1))) void*)(g),
        (__attribute__((address_space(3))) void*)(l),
        16, 0, 0);
}

#define MFMA16(a, b, c)  __builtin_amdgcn_mfma_f32_16x16x32_bf16(a, b, c, 0, 0, 0)

// ---------------------------------------------------------------------------
// Fused f32 -> bf16 convert for x (2M), w_attn (3M), w_proj (1M); 8 elem/thread
// ---------------------------------------------------------------------------
__global__ __launch_bounds__(256) void cvt_all(
    const float* __restrict__ x, const float* __restrict__ wa,
    const float* __restrict__ wp,
    bf16* __restrict__ xb, bf16* __restrict__ wab, bf16* __restrict__ wpb)
{
    const int i = blockIdx.x * 256 + threadIdx.x;     // < 786432
    const float* src; bf16* dst; int off;
    if (i < 262144)      { src = x;  dst = xb;  off = i; }
    else if (i < 655360) { src = wa; dst = wab; off = i - 262144; }
    else                 { src = wp; dst = wpb; off = i - 655360; }
    const float4 a = ((const float4*)src)[off * 2];
    const float4 b = ((const float4*)src)[off * 2 + 1];
    bf16x8 o;
    o[0] = (bf16)a.x; o[1] = (bf16)a.y; o[2] = (bf16)a.z; o[3] = (bf16)a.w;
    o[4] = (bf16)b.x; o[5] = (bf16)b.y; o[6] = (bf16)b.z; o[7] = (bf16)b.w;
    *(bf16x8*)(dst + (size_t)off * 8) = o;
}

// ---------------------------------------------------------------------------
// NT GEMM: out[m,n] = sum_k A[m,k]*B[n,k] + bias[n].  A: Mx1024, B: Nx1024 bf16.
// BK=64, double-buffered LDS, ONE barrier per k-step (prefetch issued right
// after the barrier). XOR-chunk swizzle on the GLOBAL side -> conflict-free
// b128 LDS reads.  TM=128/TN=64 (qkv) or TM=64/TN=64 (proj).
// MODE 0: N=3072. Scatter Q->[h][t][d], K->[h][t][d], V->Vt[h][d][t].
// MODE 1: f32 row-major store (proj output).
// ---------------------------------------------------------------------------
template<int MODE, int TM, int TN>
__global__ __launch_bounds__(256) void csa_gemm_bt(
    const bf16* __restrict__ A, const bf16* __restrict__ B,
    const float* __restrict__ bias,
    void* __restrict__ out0v, bf16* __restrict__ out1, bf16* __restrict__ out2)
{
    constexpr int K   = 1024;
    constexpr int WM  = (TM == 128) ? 4 : 2;     // waves in M
    constexpr int WN  = 4 / WM;                  // waves in N
    constexpr int MT  = 2;                       // 16-row subtiles per wave
    constexpr int NT  = TN / (16 * WN);          // 4 (qkv) / 2 (proj)
    constexpr int ACH = TM / 32;                 // A 16B-chunks per thread
    constexpr int BCH = TN / 32;                 // B 16B-chunks per thread
    __shared__ __align__(16) bf16 sA[2][TM * 64];
    __shared__ __align__(16) bf16 sB[2][TN * 64];

    const int tid  = threadIdx.x;
    const int lane = tid & 63;
    const int wid  = tid >> 6;
    const int wm   = wid & (WM - 1);
    const int wn   = wid / WM;
    const int rowbase = wm * 32;
    const int colbase = wn * (TN / WN);
    const int tileM = blockIdx.x * TM;
    const int tileN = blockIdx.y * TN;

    const int fr   = lane & 15;
    const int quad = lane >> 4;
    const int f7   = fr & 7;

    auto stage = [&](int b, int k0) {
#pragma unroll
        for (int i = 0; i < ACH; i++) {
            const int cid = tid + 256 * i;
            const int row = cid >> 3, pc = cid & 7;
            gload_lds16(A + (long)(tileM + row) * K + k0 + (pc ^ (row & 7)) * 8,
                        &sA[b][0] + cid * 8);
        }
#pragma unroll
        for (int i = 0; i < BCH; i++) {
            const int cid = tid + 256 * i;
            const int row = cid >> 3, pc = cid & 7;
            gload_lds16(B + (long)(tileN + row) * K + k0 + (pc ^ (row & 7)) * 8,
                        &sB[b][0] + cid * 8);
        }
    };

    floatx4 acc[MT][NT];
#pragma unroll
    for (int i = 0; i < MT; i++)
#pragma unroll
        for (int j = 0; j < NT; j++) acc[i][j] = (floatx4){0.f, 0.f, 0.f, 0.f};

    stage(0, 0);

    for (int it = 0; it < K / 64; ++it) {
        __syncthreads();
        if (it + 1 < K / 64) stage((it + 1) & 1, (it + 1) * 64);
        const bf16* A_ = &sA[it & 1][0];
        const bf16* B_ = &sB[it & 1][0];

        bf16x8 af[MT][2], bfr[NT][2];
#pragma unroll
        for (int mt = 0; mt < MT; mt++) {
            const int row = rowbase + mt * 16 + fr;
#pragma unroll
            for (int kh = 0; kh < 2; kh++)
                af[mt][kh] = *(const bf16x8*)(A_ + row * 64 +
                                              ((kh * 4 + quad) ^ f7) * 8);
        }
#pragma unroll
        for (int nt = 0; nt < NT; nt++) {
            const int row = colbase + nt * 16 + fr;
#pragma unroll
            for (int kh = 0; kh < 2; kh++)
                bfr[nt][kh] = *(const bf16x8*)(B_ + row * 64 +
                                               ((kh * 4 + quad) ^ f7) * 8);
        }
#pragma unroll
        for (int mt = 0; mt < MT; mt++)
#pragma unroll
            for (int nt = 0; nt < NT; nt++) {
                acc[mt][nt] = MFMA16(af[mt][0], bfr[nt][0], acc[mt][nt]);
                acc[mt][nt] = MFMA16(af[mt][1], bfr[nt][1], acc[mt][nt]);
            }
    }

    // epilogue: C/D layout col = lane&15, row = quad*4 + reg
#pragma unroll
    for (int mt = 0; mt < MT; mt++) {
#pragma unroll
        for (int nt = 0; nt < NT; nt++) {
            const int gn = tileN + colbase + nt * 16 + fr;
            const float bv = bias[gn];
            const int gmb = tileM + rowbase + mt * 16 + quad * 4;
            if (MODE == 0) {
                const int which = gn >> 10;
                const int w2 = gn & 1023;
                const int hh = w2 >> 6, d = w2 & 63;
                if (which == 2) {
                    bf16x4 pk;
#pragma unroll
                    for (int r = 0; r < 4; r++) pk[r] = (bf16)(acc[mt][nt][r] + bv);
                    *(bf16x4*)(out2 + ((long)(hh * HD + d) << 11) + gmb) = pk;
                } else {
                    bf16* dst = (which == 0) ? (bf16*)out0v : out1;
#pragma unroll
                    for (int r = 0; r < 4; r++)
                        dst[((long)hh * T_DIM + gmb + r) * HD + d] =
                            (bf16)(acc[mt][nt][r] + bv);
                }
            } else {
#pragma unroll
                for (int r = 0; r < 4; r++)
                    ((float*)out0v)[(long)(gmb + r) * C_DIM + gn] =
                        acc[mt][nt][r] + bv;
            }
        }
    }
}

// ---------------------------------------------------------------------------
// Chunked causal flash attention (no-max softmax -> partials ADDITIVE).
// grid (c=4, h=16, z=32); qt = 31 - z so heaviest chunks dispatch FIRST.
// Chunk c covers k-tiles [8c, min(8c+8, qt+1)). Wave owns 16 q-rows, all k.
// SINGLE-buffered K/V staging: LDS = 8+8+8 = 24 KB -> 6 blocks/CU resident
// (was 40 KB / 4 blocks with dbuf). Bet: implicit cross-block overlap at 6
// blocks/CU hides staging latency better than explicit dbuf at 4 (m114).
// ---------------------------------------------------------------------------
__global__ __launch_bounds__(256) void csa_attn_chunk(
    const bf16* __restrict__ Qh, const bf16* __restrict__ Kh,
    const bf16* __restrict__ Vth, float* __restrict__ Opart,
    float* __restrict__ lpart, bf16* __restrict__ YY)
{
    __shared__ __align__(16) bf16 sK[64 * 64];
    __shared__ __align__(16) bf16 sV[64 * 64];
    __shared__ __align__(16) bf16 sP[4][16 * 64];

    const int c  = blockIdx.x;
    const int h  = blockIdx.y;
    const int qt = 31 - (int)blockIdx.z;         // heavy q-tiles first
    const int nk = qt + 1;
    const int kt0 = c * 8;
    if (kt0 >= nk) return;                       // invalid chunk
    const int ktend = (kt0 + 8 < nk) ? kt0 + 8 : nk;

    const int tid  = threadIdx.x;
    const int lane = tid & 63;
    const int wid  = tid >> 6;
    const int fr   = lane & 15;
    const int quad = lane >> 4;
    const int f7   = fr & 7;
    const int q0   = qt * 64;
    const int qg   = q0 + wid * 16 + fr;

    // Q B-fragments: B[n=lane&15=q][k=quad*8+j] = Q[qg][d]
    const bf16* qrow = Qh + ((long)h * T_DIM + qg) * HD;
    const bf16x8 qf0 = *(const bf16x8*)(qrow + quad * 8);
    const bf16x8 qf1 = *(const bf16x8*)(qrow + quad * 8 + 32);

    // staging: thread covers 16B chunk (row rb+32i, chunk tid&7), XOR-swizzled
    const int rb   = tid >> 3;                    // 0..31
    const int cswz = (tid & 7) ^ (rb & 7);

    auto stage = [&](int k0) {
        gload_lds16(Kh + ((long)(h * T_DIM + k0 + rb) << 6) + cswz * 8,
                    sK + tid * 8);
        gload_lds16(Kh + ((long)(h * T_DIM + k0 + rb + 32) << 6) + cswz * 8,
                    sK + 2048 + tid * 8);
        gload_lds16(Vth + ((long)(h * HD + rb) << 11) + k0 + cswz * 8,
                    sV + tid * 8);
        gload_lds16(Vth + ((long)(h * HD + rb + 32) << 11) + k0 + cswz * 8,
                    sV + 2048 + tid * 8);
    };

    float l_i = 0.f;
    floatx4 o_acc[4];
#pragma unroll
    for (int d4 = 0; d4 < 4; d4++) o_acc[d4] = (floatx4){0.f, 0.f, 0.f, 0.f};

    for (int kt = kt0; kt < ktend; ++kt) {
        if (kt > kt0) __syncthreads();           // all waves done with prev tile
        stage(kt * 64);
        __syncthreads();                          // staged data visible
        const int k0 = kt * 64;
        const bool diag = (kt == qt);

        // S^T: A=K rows, B=Q (in regs); lane owns q=lane&15, k=nt*16+quad*4+r
        float p[4][4];
#pragma unroll
        for (int nt = 0; nt < 4; nt++) {
            const bf16* kr = sK + (nt * 16 + fr) * 64;
            const bf16x8 ka0 = *(const bf16x8*)(kr + (quad ^ f7) * 8);
            const bf16x8 ka1 = *(const bf16x8*)(kr + ((quad + 4) ^ f7) * 8);
            floatx4 z = (floatx4){0.f, 0.f, 0.f, 0.f};
            z = MFMA16(ka0, qf0, z);
            z = MFMA16(ka1, qf1, z);
            const int kgb = k0 + nt * 16 + quad * 4;
#pragma unroll
            for (int r = 0; r < 4; r++) {
                const float e = __builtin_amdgcn_exp2f(z[r] * 0.1803368801f);
                p[nt][r] = (!diag || (kgb + r <= qg)) ? e : 0.f;
            }
        }

        // row sum: in-lane + 2 cross-quad shuffles
        float s = 0.f;
#pragma unroll
        for (int nt = 0; nt < 4; nt++)
#pragma unroll
            for (int r = 0; r < 4; r++) s += p[nt][r];
        s += __shfl_xor(s, 16);
        s += __shfl_xor(s, 32);
        l_i += s;

        // P -> per-wave LDS, A-layout rows, XOR-swizzled, packed b64 writes
        bf16* pw = &sP[wid][0];
#pragma unroll
        for (int nt = 0; nt < 4; nt++) {
            bf16x4 pk;
#pragma unroll
            for (int r = 0; r < 4; r++) pk[r] = (bf16)p[nt][r];
            *(bf16x4*)(pw + fr * 64 +
                       (((2 * nt + (quad >> 1)) ^ f7) * 8) + (quad & 1) * 4) = pk;
        }
        asm volatile("s_waitcnt lgkmcnt(0)" ::: "memory");
        const bf16x8 pa0 = *(const bf16x8*)(pw + fr * 64 + (quad ^ f7) * 8);
        const bf16x8 pa1 = *(const bf16x8*)(pw + fr * 64 + ((quad + 4) ^ f7) * 8);

        // O += P.V : B[n=d][k=t] from V^T rows
#pragma unroll
        for (int d4 = 0; d4 < 4; d4++) {
            const bf16* vr = sV + (d4 * 16 + fr) * 64;
            const bf16x8 vb0 = *(const bf16x8*)(vr + (quad ^ f7) * 8);
            const bf16x8 vb1 = *(const bf16x8*)(vr + ((quad + 4) ^ f7) * 8);
            o_acc[d4] = MFMA16(pa0, vb0, o_acc[d4]);
            o_acc[d4] = MFMA16(pa1, vb1, o_acc[d4]);
        }
    }

    if (kt0 == 0 && ktend == nk) {
        // single-chunk q-tile: normalize and write YY directly
        const float inv_self = 1.f / l_i;
        float inv[4];
#pragma unroll
        for (int r = 0; r < 4; r++) inv[r] = __shfl(inv_self, quad * 4 + r);
#pragma unroll
        for (int r = 0; r < 4; r++) {
            const int q = q0 + wid * 16 + quad * 4 + r;
            const int rq = q >> 10, cq = q & 1023;
#pragma unroll
            for (int d4 = 0; d4 < 4; d4++) {
                const int d = d4 * 16 + fr;
                YY[(long)(h * 128 + 2 * d + rq) * 1024 + cq] =
                    (bf16)(o_acc[d4][r] * inv[r]);
            }
        }
    } else {
        // partial store: O (C-layout scatter, f32) + l (per q row)
        const long obase = ((long)((h * 32 + qt) * 4 + c)) * 4096;
#pragma unroll
        for (int d4 = 0; d4 < 4; d4++)
#pragma unroll
            for (int r = 0; r < 4; r++)
                Opart[obase + (wid * 16 + quad * 4 + r) * 64 + d4 * 16 + fr] =
                    o_acc[d4][r];
        if (quad == 0)
            lpart[((h * 32 + qt) * 4 + c) * 64 + wid * 16 + fr] = l_i;
    }
}

// ---------------------------------------------------------------------------
// Combine partials for qt >= 8: sum <=4 chunks, normalize, write YY.
// grid (24, 16): qt = blockIdx.x + 8.
// ---------------------------------------------------------------------------
__global__ __launch_bounds__(256) void csa_combine(
    const float* __restrict__ Opart, const float* __restrict__ lpart,
    bf16* __restrict__ YY)
{
    const int qt = blockIdx.x + 8;
    const int h  = blockIdx.y;
    const int nc = (qt >> 3) + 1;               // 2..4
    const int t  = threadIdx.x;
    const int q  = t >> 2;                      // 0..63
    const int d0 = (t & 3) * 16;

    const long obase = ((long)((h * 32 + qt) * 4)) * 4096 + q * 64 + d0;
    const int  lbase = (h * 32 + qt) * 4 * 64 + q;

    float4 acc[4] = {};
    float lq = 0.f;
    for (int c = 0; c < nc; c++) {
        const float4* src = (const float4*)(Opart + obase + (long)c * 4096);
#pragma unroll
        for (int j = 0; j < 4; j++) {
            const float4 v = src[j];
            acc[j].x += v.x; acc[j].y += v.y; acc[j].z += v.z; acc[j].w += v.w;
        }
        lq += lpart[lbase + c * 64];
    }
    const float inv = 1.f / lq;
    const int qglob = qt * 64 + q;
    const int rq = qglob >> 10, cq = qglob & 1023;
#pragma unroll
    for (int j = 0; j < 4; j++) {
        const float vv[4] = {acc[j].x, acc[j].y, acc[j].z, acc[j].w};
#pragma unroll
        for (int k = 0; k < 4; k++) {
            const int d = d0 + j * 4 + k;
            YY[(long)(h * 128 + 2 * d + rq) * 1024 + cq] = (bf16)(vv[k] * inv);
        }
    }
}

extern "C" void kernel_launch(void* const* d_in, const int* in_sizes, int n_in,
                              void* d_out, int out_size, void* d_ws, size_t ws_size,
                              hipStream_t stream) {
    (void)in_sizes; (void)n_in; (void)out_size; (void)ws_size;
    const float* x      = (const float*)d_in[0];
    const float* w_attn = (const float*)d_in[1];
    const float* b_attn = (const float*)d_in[2];
    const float* w_proj = (const float*)d_in[3];
    const float* b_proj = (const float*)d_in[4];

    // workspace layout
    bf16* xb  = (bf16*)d_ws;                          // [T][C]
    bf16* wab = xb  + (size_t)T_DIM * C_DIM;          // [3C][C]
    bf16* wpb = wab + (size_t)3 * C_DIM * C_DIM;      // [C][C]
    bf16* Q   = wpb + (size_t)C_DIM * C_DIM;          // [NH][T][HD]
    bf16* Kp  = Q   + (size_t)NH * T_DIM * HD;        // [NH][T][HD]
    bf16* Vt  = Kp  + (size_t)NH * T_DIM * HD;        // [NH][HD][T]
    bf16* YY  = Vt  + (size_t)NH * T_DIM * HD;        // [T][C] permuted pre-proj
    float* Opart = (float*)(YY + (size_t)T_DIM * C_DIM);   // [16][32][4][64][64]
    float* lpart = Opart + (size_t)16 * 32 * 4 * 4096;     // [16][32][4][64]

    // fused f32->bf16 conversion (x, w_attn, w_proj)
    cvt_all<<<3072, 256, 0, stream>>>(x, w_attn, w_proj, xb, wab, wpb);

    // qkv projection: 128x64 tiles, BK=64 dbuf, 768 blocks = 3/CU
    csa_gemm_bt<0, 128, 64><<<dim3(16, 48), 256, 0, stream>>>(xb, wab, b_attn, Q, Kp, Vt);
    // chunked causal flash attention (single-buffer, 6 blocks/CU) + combine
    csa_attn_chunk<<<dim3(4, NH, 32), 256, 0, stream>>>(Q, Kp, Vt, Opart, lpart, YY);
    csa_combine<<<dim3(24, NH), 256, 0, stream>>>(Opart, lpart, YY);
    // output projection: 64x64 tiles, BK=64 dbuf, 512 blocks = 2/CU
    csa_gemm_bt<1, 64, 64><<<dim3(32, 16), 256, 0, stream>>>(YY, wpb, b_proj, d_out, nullptr, nullptr);
}